// Round 2
// baseline (120.976 us; speedup 1.0000x reference)
//
#include <hip/hip_runtime.h>

// ---------------------------------------------------------------------------
// relu-attention block:
//   theta/phi/psi = 1x1conv(z) [B,64,N]; g = phi^T psi; P = relu(g/N);
//   tmp = P theta^T; out = w_v tmp + b_v + z.   B=2, Ci=128, Co=64, N=4096.
// K1: projections -> Q(phi)[b][n][64], K(psi)[b][n][64], V(theta^T)[b][o][n], bf16
// K2: fused P-attention + epilogue projection + residual.
// ---------------------------------------------------------------------------

#define NSEQ 4096
#define CI 128
#define CO 64

typedef __attribute__((ext_vector_type(8))) short bf16x8;   // 8 bf16 = 4 VGPR
typedef __attribute__((ext_vector_type(4))) short bf16x4;
typedef __attribute__((ext_vector_type(4))) float f32x4;

static __device__ inline short f2bf(float f) {
  union { float f; unsigned u; } v; v.f = f;
  unsigned r = v.u + 0x7fffu + ((v.u >> 16) & 1u);   // RNE
  return (short)(r >> 16);
}

// ---------------------------------------------------------------------------
// Kernel 1: projections. grid = B * (N/64) = 128 WGs, 256 threads.
// ---------------------------------------------------------------------------
__global__ __launch_bounds__(256, 1) void proj_kernel(
    const float* __restrict__ z,
    const float* __restrict__ w_th, const float* __restrict__ b_th,
    const float* __restrict__ w_ph, const float* __restrict__ b_ph,
    const float* __restrict__ w_ps, const float* __restrict__ b_ps,
    short* __restrict__ Qg, short* __restrict__ Kg, short* __restrict__ Vt)
{
  __shared__ f32x4 zt4[16384 / 16];        // z^T tile [64 n][128 c] bf16, swizzled
  char* zt = (char*)zt4;

  const int wgid = blockIdx.x;
  const int b = wgid >> 6;
  const int n0 = (wgid & 63) * 64;
  const int t = threadIdx.x;

  // ---- stage z^T tile (transpose fp32 [c][n] -> bf16 LDS [n][c], swizzled) ----
  {
    const int ck = t & 15;        // 16B chunk within a 256B z-row segment (4 n)
    const int cr = t >> 4;        // c row within group of 16
#pragma unroll
    for (int g = 0; g < 8; ++g) {
      const int c = g * 16 + cr;
      f32x4 v = *(const f32x4*)(z + (size_t)(b * CI + c) * NSEQ + n0 + ck * 4);
#pragma unroll
      for (int i = 0; i < 4; ++i) {
        const int n = ck * 4 + i;
        const int chunk = (c >> 3) ^ (n & 7);     // 16 chunks/row, XOR-swizzle
        *(short*)(zt + n * 256 + chunk * 16 + (c & 7) * 2) = f2bf(v[i]);
      }
    }
  }
  __syncthreads();

  const int w = t >> 6, l = t & 63, lr = l & 15, lg = l >> 4;
  const int nw = w * 16;                    // wave's 16 rows within the 64-row tile
  const f32x4 zero4 = {0.f, 0.f, 0.f, 0.f};

  // A-frags: rows n, k = c (4 ksteps of 32)
  bf16x8 a[4];
#pragma unroll
  for (int ks = 0; ks < 4; ++ks) {
    const int n = nw + lr;
    const int chunk = (ks * 4 + lg) ^ (n & 7);
    a[ks] = *(const bf16x8*)(zt + n * 256 + chunk * 16);
  }

  const float* Ws[3]   = {w_ph, w_ps, w_th};   // mat0->Q(phi), 1->K(psi), 2->V(theta)
  const float* Bias[3] = {b_ph, b_ps, b_th};

#pragma unroll
  for (int mat = 0; mat < 3; ++mat) {
    const float* W = Ws[mat];
#pragma unroll
    for (int osub = 0; osub < 4; ++osub) {
      const int o = osub * 16 + lr;
      f32x4 acc = zero4;
#pragma unroll
      for (int ks = 0; ks < 4; ++ks) {
        const float* wp = W + o * CI + ks * 32 + lg * 8;   // W[o][c..c+7]
        f32x4 x0 = *(const f32x4*)wp;
        f32x4 x1 = *(const f32x4*)(wp + 4);
        bf16x8 bf;
#pragma unroll
        for (int j = 0; j < 4; ++j) { bf[j] = f2bf(x0[j]); bf[4 + j] = f2bf(x1[j]); }
        acc = __builtin_amdgcn_mfma_f32_16x16x32_bf16(a[ks], bf, acc, 0, 0, 0);
      }
      const float bias = Bias[mat][o];
      // D: col = o (lane&15), row n = nw + lg*4 + r
      if (mat == 2) {
        bf16x4 pk;
#pragma unroll
        for (int r = 0; r < 4; ++r) pk[r] = f2bf(acc[r] + bias);
        *(bf16x4*)(Vt + (size_t)(b * CO + o) * NSEQ + n0 + nw + lg * 4) = pk;
      } else {
        short* dst = (mat == 0 ? Qg : Kg) + (size_t)(b * NSEQ + n0 + nw + lg * 4) * CO + o;
#pragma unroll
        for (int r = 0; r < 4; ++r) dst[(size_t)r * CO] = f2bf(acc[r] + bias);
      }
    }
  }
}

// ---------------------------------------------------------------------------
// Kernel 2: fused relu-attention + output projection + residual.
// grid = B * (N/32) = 256 WGs, 256 threads (4 waves).
// Waves 0,1: rows 0-15 / 16-31 on m-tile parity 0; waves 2,3: same rows, parity 1.
// LDS: [K0 8K][K1 8K][V0 8K][V1 8K][P: 4 x 2K] = 40 KB, XOR-swizzled 16B chunks.
// ---------------------------------------------------------------------------
__global__ __launch_bounds__(256, 1) void attn_kernel(
    const short* __restrict__ Qg, const short* __restrict__ Kg,
    const short* __restrict__ Vt, const float* __restrict__ w_v,
    const float* __restrict__ b_v, const float* __restrict__ z,
    float* __restrict__ out)
{
  __shared__ f32x4 smem4[40960 / 16];
  char* smem = (char*)smem4;

  const int wg = blockIdx.x;
  const int b = wg >> 7;
  const int nt = wg & 127;
  const int n0 = nt * 32;
  const int t = threadIdx.x;
  const int w = t >> 6;
  const int l = t & 63;
  const int lr = l & 15;
  const int lg = l >> 4;
  const int tw = w >> 1;                 // m-tile parity this wave owns
  const int nbase = n0 + (w & 1) * 16;   // wave's 16 Q rows
  const f32x4 zero4 = {0.f, 0.f, 0.f, 0.f};

  // Q A-frags (persistent)
  bf16x8 q0, q1;
  {
    const short* qp = Qg + (size_t)(b * NSEQ + nbase + lr) * CO + lg * 8;
    q0 = *(const bf16x8*)qp;
    q1 = *(const bf16x8*)(qp + 32);
  }

  f32x4 oacc[4];
#pragma unroll
  for (int i = 0; i < 4; ++i) oacc[i] = zero4;

  char* Pb = smem + 32768 + w * 2048;    // wave-private P [16 n][64 m] bf16, swizzled

  bf16x8 stg[8];
  // regions per 512 chunks: 0->K tile0, 1->K tile1, 2->V tile0, 3->V tile1
  auto load_stage = [&](int ss) {
    const int m0 = ss * 128;
#pragma unroll
    for (int r = 0; r < 8; ++r) {
      const int chunk = r * 256 + w * 64 + l;
      const int row = (chunk >> 3) & 63;
      const int lc = chunk & 7;
      const short* src;
      if (r < 4) {  // K [m][c]
        const int m = m0 + (chunk >> 9) * 64 + row;
        src = Kg + (size_t)(b * NSEQ + m) * CO + lc * 8;
      } else {      // V^T [o][m]
        src = Vt + (size_t)(b * CO + row) * NSEQ + m0 + ((chunk >> 9) - 2) * 64 + lc * 8;
      }
      stg[r] = *(const bf16x8*)src;
    }
  };
  auto write_stage = [&]() {
#pragma unroll
    for (int r = 0; r < 8; ++r) {
      const int chunk = r * 256 + w * 64 + l;
      const int row = (chunk >> 3) & 63;
      const int pc = (chunk & 7) ^ (row & 7);
      *(bf16x8*)(smem + (chunk >> 9) * 8192 + row * 128 + pc * 16) = stg[r];
    }
  };

  load_stage(0);
  write_stage();
  __syncthreads();

  const char* Kt  = smem + tw * 8192;
  const char* Vtl = smem + 16384 + tw * 8192;

  for (int ss = 0; ss < 32; ++ss) {
    if (ss < 31) load_stage(ss + 1);     // global loads in flight during compute

    // ---- S = Q K^T, relu/scale -> P (LDS layout fixup) ----
#pragma unroll
    for (int msub = 0; msub < 4; ++msub) {
      const int m = msub * 16 + lr;
      bf16x8 k0 = *(const bf16x8*)(Kt + m * 128 + ((lg ^ (m & 7)) * 16));
      bf16x8 k1 = *(const bf16x8*)(Kt + m * 128 + (((4 + lg) ^ (m & 7)) * 16));
      f32x4 s = __builtin_amdgcn_mfma_f32_16x16x32_bf16(q0, k0, zero4, 0, 0, 0);
      s = __builtin_amdgcn_mfma_f32_16x16x32_bf16(q1, k1, s, 0, 0, 0);
#pragma unroll
      for (int r = 0; r < 4; ++r) {
        const int nl = lg * 4 + r;
        const int ml = msub * 16 + lr;
        const float p = s[r] > 0.f ? s[r] * (1.f / 4096.f) : 0.f;
        *(short*)(Pb + nl * 128 + ((2 * ml) ^ ((nl & 7) << 4))) = f2bf(p);
      }
    }
    // ---- O += P V ----
    bf16x8 pa0 = *(const bf16x8*)(Pb + lr * 128 + ((lg ^ (lr & 7)) * 16));
    bf16x8 pa1 = *(const bf16x8*)(Pb + lr * 128 + (((4 + lg) ^ (lr & 7)) * 16));
#pragma unroll
    for (int osub = 0; osub < 4; ++osub) {
      const int o = osub * 16 + lr;
      bf16x8 v0 = *(const bf16x8*)(Vtl + o * 128 + ((lg ^ (o & 7)) * 16));
      bf16x8 v1 = *(const bf16x8*)(Vtl + o * 128 + (((4 + lg) ^ (o & 7)) * 16));
      oacc[osub] = __builtin_amdgcn_mfma_f32_16x16x32_bf16(pa0, v0, oacc[osub], 0, 0, 0);
      oacc[osub] = __builtin_amdgcn_mfma_f32_16x16x32_bf16(pa1, v1, oacc[osub], 0, 0, 0);
    }

    __syncthreads();                     // everyone done reading current tiles
    if (ss < 31) {
      write_stage();                     // overwrite buffers with next superstep
      __syncthreads();
    }
  }

  // ---- reduce wave pairs (0,2) and (1,3) through LDS ----
  float* ored = (float*)smem;            // reuse K region: 2 x [16][64] f32 = 8KB
  if (tw == 1) {
    float* dst = ored + (w & 1) * 1024;
#pragma unroll
    for (int osub = 0; osub < 4; ++osub)
#pragma unroll
      for (int r = 0; r < 4; ++r)
        dst[(lg * 4 + r) * 64 + osub * 16 + lr] = oacc[osub][r];
  }
  __syncthreads();

  if (tw == 0) {
    const float* sp = ored + (w & 1) * 1024;
    // sum partials, convert O -> bf16 into swizzled Pb (D-layout -> A-layout fixup)
#pragma unroll
    for (int osub = 0; osub < 4; ++osub) {
#pragma unroll
      for (int r = 0; r < 4; ++r) {
        const float v = oacc[osub][r] + sp[(lg * 4 + r) * 64 + osub * 16 + lr];
        const int nl = lg * 4 + r;
        const int ol = osub * 16 + lr;
        *(short*)(Pb + nl * 128 + ((2 * ol) ^ ((nl & 7) << 4))) = f2bf(v);
      }
    }
    bf16x8 oa0 = *(const bf16x8*)(Pb + lr * 128 + ((lg ^ (lr & 7)) * 16));
    bf16x8 oa1 = *(const bf16x8*)(Pb + lr * 128 + (((4 + lg) ^ (lr & 7)) * 16));

    // epilogue: out[b][ci][n] = sum_o O[n][o] w_v[ci][o] + b_v[ci] + z
#pragma unroll
    for (int cis = 0; cis < 8; ++cis) {
      const int ci = cis * 16 + lr;
      const float* wp = w_v + ci * CO + lg * 8;
      f32x4 wa0 = *(const f32x4*)wp;
      f32x4 wa1 = *(const f32x4*)(wp + 4);
      f32x4 wb0 = *(const f32x4*)(wp + 32);
      f32x4 wb1 = *(const f32x4*)(wp + 36);
      bf16x8 wf0, wf1;
#pragma unroll
      for (int j = 0; j < 4; ++j) {
        wf0[j] = f2bf(wa0[j]); wf0[4 + j] = f2bf(wa1[j]);
        wf1[j] = f2bf(wb0[j]); wf1[4 + j] = f2bf(wb1[j]);
      }
      f32x4 e = __builtin_amdgcn_mfma_f32_16x16x32_bf16(oa0, wf0, zero4, 0, 0, 0);
      e = __builtin_amdgcn_mfma_f32_16x16x32_bf16(oa1, wf1, e, 0, 0, 0);

      const size_t off = (size_t)(b * CI + ci) * NSEQ + nbase + lg * 4;
      f32x4 zv = *(const f32x4*)(z + off);
      const float bias = b_v[ci];
      f32x4 res;
#pragma unroll
      for (int r = 0; r < 4; ++r) res[r] = e[r] + zv[r] + bias;
      *(f32x4*)(out + off) = res;         // 4 consecutive n: coalesced 16B store
    }
  }
}

// ---------------------------------------------------------------------------
extern "C" void kernel_launch(void* const* d_in, const int* in_sizes, int n_in,
                              void* d_out, int out_size, void* d_ws, size_t ws_size,
                              hipStream_t stream) {
  const float* z    = (const float*)d_in[0];
  const float* w_th = (const float*)d_in[1];
  const float* b_th = (const float*)d_in[2];
  const float* w_ph = (const float*)d_in[3];
  const float* b_ph = (const float*)d_in[4];
  const float* w_ps = (const float*)d_in[5];
  const float* b_ps = (const float*)d_in[6];
  const float* w_v  = (const float*)d_in[7];
  const float* b_v  = (const float*)d_in[8];
  float* out = (float*)d_out;

  short* Qg = (short*)d_ws;                       // [2][4096][64] bf16 = 1 MB
  short* Kg = Qg + 2 * NSEQ * CO;                 // [2][4096][64] bf16 = 1 MB
  short* Vt = Kg + 2 * NSEQ * CO;                 // [2][64][4096] bf16 = 1 MB

  proj_kernel<<<128, 256, 0, stream>>>(z, w_th, b_th, w_ph, b_ph, w_ps, b_ps,
                                       Qg, Kg, Vt);
  attn_kernel<<<256, 256, 0, stream>>>(Qg, Kg, Vt, w_v, b_v, z, out);
}